// Round 2
// 188.356 us; speedup vs baseline: 1.0221x; 1.0221x over previous
//
#include <hip/hip_runtime.h>
#include <stdint.h>

typedef _Float16 v8h __attribute__((ext_vector_type(8)));
typedef _Float16 v2h __attribute__((ext_vector_type(2)));
typedef float v4f __attribute__((ext_vector_type(4)));

#define NPTS 2048
#define BATCH 16
#define KNN 20
#define PAIRS (NPTS * KNN)   // 40960 per batch

// ---------- helpers ----------
// R6: bf16 -> fp16 for p/q/h2/W3. pair op drops from ~13 VALU ops (unpack +
// f32 add/max + round/repack) to 2 packed ops (v_pk_add_f16 + v_pk_max_f16).
// R7: use native _Float16 vectors (ROCm header's __hmax2 overload was broken).
__device__ __forceinline__ unsigned pair_relu_h2(unsigned pu, unsigned qu) {
  v2h a = *(const v2h*)&pu;
  v2h b = *(const v2h*)&qu;
  v2h s = a + b;                                   // v_pk_add_f16
  v2h z = {(_Float16)0.f, (_Float16)0.f};
  v2h r = __builtin_elementwise_max(s, z);         // v_pk_max_f16 (relu)
  return *(const unsigned*)&r;
}

// ---------- K0: fold M2a = W2*W1a, M2b = W2*(W1b-W1a); zero H ----------
__global__ void prep_kernel(const float* __restrict__ W1, const float* __restrict__ W2,
                            float* __restrict__ M2a, float* __restrict__ M2b,
                            int* __restrict__ H) {
  if (blockIdx.x == 0 && threadIdx.x < 128) {
    int o = threadIdx.x;
    float a0 = 0, a1 = 0, a2 = 0, b0 = 0, b1 = 0, b2 = 0;
    for (int i = 0; i < 64; ++i) {
      float w2 = W2[o * 64 + i];
      const float* w1r = W1 + i * 6;
      a0 += w2 * w1r[0]; a1 += w2 * w1r[1]; a2 += w2 * w1r[2];
      b0 += w2 * (w1r[3] - w1r[0]); b1 += w2 * (w1r[4] - w1r[1]); b2 += w2 * (w1r[5] - w1r[2]);
    }
    M2a[o * 3 + 0] = a0; M2a[o * 3 + 1] = a1; M2a[o * 3 + 2] = a2;
    M2b[o * 3 + 0] = b0; M2b[o * 3 + 1] = b1; M2b[o * 3 + 2] = b2;
  }
  int g = blockIdx.x * 128 + threadIdx.x;
  if (g < BATCH * 256) H[g] = 0;
}

// ---------- K1: p[b][j][o] = M2a[o]·x_j ; q likewise (fp16, packed pairs) ----------
__global__ __launch_bounds__(64) void pq_kernel(const float* __restrict__ x,
                                                const float* __restrict__ M2a,
                                                const float* __restrict__ M2b,
                                                unsigned short* __restrict__ p,
                                                unsigned short* __restrict__ q) {
  int b = blockIdx.x >> 6;
  int j0 = (blockIdx.x & 63) << 5;
  int t = threadIdx.x;                 // 0..63 -> channels 2t, 2t+1
  int o0 = t * 2;
  float a00 = M2a[o0 * 3 + 0], a01 = M2a[o0 * 3 + 1], a02 = M2a[o0 * 3 + 2];
  float a10 = M2a[o0 * 3 + 3], a11 = M2a[o0 * 3 + 4], a12 = M2a[o0 * 3 + 5];
  float b00 = M2b[o0 * 3 + 0], b01 = M2b[o0 * 3 + 1], b02 = M2b[o0 * 3 + 2];
  float b10 = M2b[o0 * 3 + 3], b11 = M2b[o0 * 3 + 4], b12 = M2b[o0 * 3 + 5];
  const float* xb = x + b * 3 * NPTS;
  unsigned* pw = (unsigned*)p;
  unsigned* qw = (unsigned*)q;
  for (int jj = 0; jj < 32; ++jj) {
    int j = j0 + jj;
    float x0 = xb[j], x1 = xb[NPTS + j], x2 = xb[2 * NPTS + j];
    float p0 = a00 * x0 + a01 * x1 + a02 * x2;
    float p1 = a10 * x0 + a11 * x1 + a12 * x2;
    float q0 = b00 * x0 + b01 * x1 + b02 * x2;
    float q1 = b10 * x0 + b11 * x1 + b12 * x2;
    size_t base = ((size_t)(b * NPTS + j)) * 64 + t;   // dword index
    auto hp = __builtin_amdgcn_cvt_pkrtz(p0, p1);      // v_cvt_pkrtz_f16_f32
    auto hq = __builtin_amdgcn_cvt_pkrtz(q0, q1);
    pw[base] = *(const unsigned*)&hp;
    qw[base] = *(const unsigned*)&hq;
  }
}

// ---------- K2: exact 20-NN, 4 queries per wave ----------
// R4 post-mortem: per-query LDS traffic (49KB) over the 69 TB/s LDS pipe was
// the floor (~23us at 1 query/wave). R5: 4 queries/wave share each point read
// -> LDS traffic /4. cand[] is wave-private -> pass2 + select need NO barrier.
// tau inflation (2^-18) carried from R3 (cross-pass FMA-contraction ulps).
__global__ __launch_bounds__(256) void knn_kernel(const float* __restrict__ x,
                                                  int* __restrict__ idxOut) {
  __shared__ float px[NPTS], py[NPTS], pz[NPTS];      // 24 KB, stride-4B: conflict-free
  __shared__ unsigned long long cand[4][4][128];      // 16 KB, wave-private
  int b = blockIdx.x >> 7;
  int qblk = blockIdx.x & 127;
  const float* xb = x + b * 3 * NPTS;
  for (int i = threadIdx.x; i < NPTS; i += 256) {
    px[i] = xb[i]; py[i] = xb[NPTS + i]; pz[i] = xb[2 * NPTS + i];
  }
  __syncthreads();
  int wid = threadIdx.x >> 6, lane = threadIdx.x & 63;
  int qbase = qblk * 16 + wid * 4;                    // 4 queries per wave

  float qx[4], qy[4], qz[4], mn[4];
#pragma unroll
  for (int g = 0; g < 4; ++g) {
    qx[g] = px[qbase + g]; qy[g] = py[qbase + g]; qz[g] = pz[qbase + g];
    mn[g] = 1e30f;
  }

  // pass 1: per-lane min over its 32 points, for all 4 queries (shared loads)
  for (int s = 0; s < 32; ++s) {
    int i = s * 64 + lane;
    float X = px[i], Y = py[i], Z = pz[i];
#pragma unroll
    for (int g = 0; g < 4; ++g) {
      float dx = X - qx[g], dy = Y - qy[g], dz = Z - qz[g];
      mn[g] = fminf(mn[g], dx * dx + dy * dy + dz * dz);
    }
  }

  // tau[g] = 20th-smallest lane-min (upper bound on d_(20)), inflated
  float tau[4];
#pragma unroll
  for (int g = 0; g < 4; ++g) {
    float v = mn[g];
    for (int k = 2; k <= 64; k <<= 1) {
      for (int j = k >> 1; j > 0; j >>= 1) {
        float o = __shfl_xor(v, j);
        bool low = (lane & j) == 0;
        bool up = (lane & k) == 0;
        v = (low == up) ? fminf(v, o) : fmaxf(v, o);
      }
    }
    tau[g] = __shfl(v, 19) * (1.0f + 3.8e-6f);
  }

  // pass 2: recompute (shared loads), ballot-compact candidates per query
  int cnt[4] = {0, 0, 0, 0};
  for (int s = 0; s < 32; ++s) {
    int i = s * 64 + lane;
    float X = px[i], Y = py[i], Z = pz[i];
#pragma unroll
    for (int g = 0; g < 4; ++g) {
      float dx = X - qx[g], dy = Y - qy[g], dz = Z - qz[g];
      float d = dx * dx + dy * dy + dz * dz;
      bool take = d <= tau[g];
      unsigned long long mb = __ballot(take);
      if (take) {
        int pos = cnt[g] + __popcll(mb & ((1ull << lane) - 1ull));
        if (pos < 128)
          cand[wid][g][pos] =
              (((unsigned long long)__float_as_uint(d)) << 32) | (unsigned)i;
      }
      cnt[g] += __popcll(mb);
    }
  }
  // cand written & read by the same wave: no __syncthreads needed.

  // rank-count select per query: broadcast reads (same addr all lanes = free).
  // Keys unique (index tiebreak) -> exact ranks; winners rank<20 write slot rank.
#pragma unroll
  for (int g = 0; g < 4; ++g) {
    int nc = cnt[g] < 128 ? cnt[g] : 128;
    unsigned long long k0 = (lane < nc) ? cand[wid][g][lane] : ~0ull;
    unsigned long long k1 = (lane + 64 < nc) ? cand[wid][g][lane + 64] : ~0ull;
    int r0 = 0, r1 = 0;
    for (int i = 0; i < nc; ++i) {
      unsigned long long ki = cand[wid][g][i];
      r0 += (ki < k0) ? 1 : 0;
      r1 += (ki < k1) ? 1 : 0;
    }
    long long obase = ((long long)b * NPTS + qbase + g) * KNN;
    if (lane < nc && r0 < KNN) idxOut[obase + r0] = (int)(k0 & 0xffffffffu);
    if (lane + 64 < nc && r1 < KNN) idxOut[obase + r1] = (int)(k1 & 0xffffffffu);
  }
}

// ---------- K3: h3 = relu(W3 · relu(p_j+q_n)) via MFMA, fused max-reduce ----------
// R5: grid 768->1536 (6 blocks/CU at VGPR=80; R4 measured occupancy 28% with
// grid=3/CU as the cap). Structure unchanged (prefetch depth 1, 16-pair tile).
// R6/R7: fp16 activations + mfma_f32_16x16x32_f16. Staging conversion was the
// VALU bottleneck (41% VALUBusy vs 23% MfmaUtil): ~52 VALU ops/thread/tile
// for bf16 unpack/add/max/repack -> 8 packed fp16 ops. Same fragment layout.
__global__ __launch_bounds__(256, 2) void gemm_max_kernel(
    const unsigned short* __restrict__ p, const unsigned short* __restrict__ q,
    const int* __restrict__ idx, const float* __restrict__ W3, int* __restrict__ H) {
  __shared__ __align__(16) unsigned short h2s[2][16 * 136];  // 8704 B double-buffered tile

  int b = blockIdx.x & 15;
  int w = blockIdx.x >> 4;  // 0..95
  int t = threadIdx.x;
  int lane = t & 63, wid = t >> 6;
  int r16 = lane & 15, quad = lane >> 4;

  // Preload all B fragments (W3^T rows, fp16) into registers: 4 ntiles x 4 ksteps
  v8h bfr[4][4];
#pragma unroll
  for (int ntl = 0; ntl < 4; ++ntl) {
#pragma unroll
    for (int kk = 0; kk < 4; ++kk) {
      int n = (wid * 4 + ntl) * 16 + r16;
      const float* src = W3 + n * 128 + kk * 32 + quad * 8;
      v8h f;
#pragma unroll
      for (int jj = 0; jj < 8; ++jj)
        f[jj] = (_Float16)src[jj];           // v_cvt_f16_f32
      bfr[ntl][kk] = f;
    }
  }

  const unsigned short* pB = p + (size_t)b * NPTS * 128;
  const unsigned short* qB = q + (size_t)b * NPTS * 128;
  const int* idxB = idx + (size_t)b * PAIRS;

  int pm = t >> 4;        // pair-in-tile 0..15
  int cseg = t & 15;      // 8-channel segment

  // prologue prefetch for first tile
  uint4 P4n, Q4n;
  {
    int pr = w * 16 + pm;
    int n0 = pr / 20;
    int j0 = idxB[pr] & (NPTS - 1);
    P4n = *(const uint4*)(pB + (size_t)j0 * 128 + cseg * 8);
    Q4n = *(const uint4*)(qB + (size_t)n0 * 128 + cseg * 8);
  }

  float vmx[4] = {0.f, 0.f, 0.f, 0.f};
  int buf = 0;
  for (int T = w; T < PAIRS / 16; T += 96) {
    // stage h2 tile (16 pairs x 128 ch, fp16) from prefetched regs
    uint4 R;
    R.x = pair_relu_h2(P4n.x, Q4n.x);
    R.y = pair_relu_h2(P4n.y, Q4n.y);
    R.z = pair_relu_h2(P4n.z, Q4n.z);
    R.w = pair_relu_h2(P4n.w, Q4n.w);
    *(uint4*)&h2s[buf][pm * 136 + cseg * 8] = R;
    __syncthreads();

    // prefetch next tile (consumed next iteration; latency hidden by MFMA)
    int Tn = T + 96;
    if (Tn < PAIRS / 16) {
      int prn = Tn * 16 + pm;
      int nn = prn / 20;
      int jn = idxB[prn] & (NPTS - 1);
      P4n = *(const uint4*)(pB + (size_t)jn * 128 + cseg * 8);
      Q4n = *(const uint4*)(qB + (size_t)nn * 128 + cseg * 8);
    }

    // A fragments: A[m=lane&15][k=quad*8+j]
    v8h a[4];
#pragma unroll
    for (int kk = 0; kk < 4; ++kk)
      a[kk] = *(const v8h*)&h2s[buf][r16 * 136 + kk * 32 + quad * 8];

#pragma unroll
    for (int ntl = 0; ntl < 4; ++ntl) {
      v4f acc = {0.f, 0.f, 0.f, 0.f};
#pragma unroll
      for (int kk = 0; kk < 4; ++kk)
        acc = __builtin_amdgcn_mfma_f32_16x16x32_f16(a[kk], bfr[ntl][kk], acc, 0, 0, 0);
      // relu folds into max (vmx starts at 0); acc rows = pairs, col = channel
      vmx[ntl] = fmaxf(vmx[ntl], fmaxf(fmaxf(acc[0], acc[1]), fmaxf(acc[2], acc[3])));
    }
    buf ^= 1;
  }

  // reduce across quads (rows are pairs -> max over all), then global atomicMax
#pragma unroll
  for (int ntl = 0; ntl < 4; ++ntl) {
    float vv = vmx[ntl];
    vv = fmaxf(vv, __shfl_xor(vv, 16));
    vv = fmaxf(vv, __shfl_xor(vv, 32));
    if (quad == 0) {
      int ch = (wid * 4 + ntl) * 16 + r16;
      atomicMax(&H[b * 256 + ch], __float_as_int(vv));  // values >= 0: int order == float order
    }
  }
}

// ---------- K4: out = H @ fc_w^T + fc_b (one wave per output element) ----------
__global__ __launch_bounds__(64) void fc_kernel(const int* __restrict__ Hi,
                                                const float* __restrict__ fcw,
                                                const float* __restrict__ fcb,
                                                float* __restrict__ out) {
  int b = blockIdx.x / 10, r = blockIdx.x % 10;
  int lane = threadIdx.x;
  const float* Hb = (const float*)Hi + b * 256;
  float s = 0.f;
#pragma unroll
  for (int c = lane; c < 256; c += 64) s += Hb[c] * fcw[r * 256 + c];
#pragma unroll
  for (int m = 32; m > 0; m >>= 1) s += __shfl_xor(s, m);
  if (lane == 0) out[b * 10 + r] = s + fcb[r];
}

// ---------- launch ----------
extern "C" void kernel_launch(void* const* d_in, const int* in_sizes, int n_in,
                              void* d_out, int out_size, void* d_ws, size_t ws_size,
                              hipStream_t stream) {
  const float* x   = (const float*)d_in[0];
  const float* W1  = (const float*)d_in[1];
  const float* W2  = (const float*)d_in[2];
  const float* W3  = (const float*)d_in[3];
  const float* fcw = (const float*)d_in[4];
  const float* fcb = (const float*)d_in[5];
  float* out = (float*)d_out;
  char* ws = (char*)d_ws;

  // workspace layout (needs ~20 MB)
  float* M2a = (float*)(ws + 0);            // 1536 B
  float* M2b = (float*)(ws + 1536);         // 1536 B
  int* H     = (int*)(ws + 4096);           // 16 KB (16x256 f32-as-int)
  int* idx   = (int*)(ws + 24576);          // 2.62 MB
  unsigned short* p = (unsigned short*)(ws + 3145728);   // 8.39 MB fp16
  unsigned short* q = (unsigned short*)(ws + 12582912);  // 8.39 MB fp16

  prep_kernel<<<32, 128, 0, stream>>>(W1, W2, M2a, M2b, H);
  pq_kernel<<<BATCH * 64, 64, 0, stream>>>(x, M2a, M2b, p, q);
  knn_kernel<<<BATCH * 128, 256, 0, stream>>>(x, idx);
  gemm_max_kernel<<<BATCH * 96, 256, 0, stream>>>(p, q, idx, W3, H);
  fc_kernel<<<BATCH * 10, 64, 0, stream>>>(H, fcw, fcb, out);
}

// Round 3
// 177.410 us; speedup vs baseline: 1.0852x; 1.0617x over previous
//
#include <hip/hip_runtime.h>
#include <stdint.h>

typedef _Float16 v8h __attribute__((ext_vector_type(8)));
typedef _Float16 v2h __attribute__((ext_vector_type(2)));
typedef float v4f __attribute__((ext_vector_type(4)));
typedef float v16f __attribute__((ext_vector_type(16)));

#define NPTS 2048
#define BATCH 16
#define KNN 20
#define PAIRS (NPTS * KNN)   // 40960 per batch

// ---------- helpers ----------
// R6/R7: fp16 pair op: 2 packed ops (v_pk_add_f16 + v_pk_max_f16).
__device__ __forceinline__ unsigned pair_relu_h2(unsigned pu, unsigned qu) {
  v2h a = *(const v2h*)&pu;
  v2h b = *(const v2h*)&qu;
  v2h s = a + b;                                   // v_pk_add_f16
  v2h z = {(_Float16)0.f, (_Float16)0.f};
  v2h r = __builtin_elementwise_max(s, z);         // v_pk_max_f16 (relu)
  return *(const unsigned*)&r;
}

// ---------- K0: fold M2a = W2*W1a, M2b = W2*(W1b-W1a); zero H ----------
__global__ void prep_kernel(const float* __restrict__ W1, const float* __restrict__ W2,
                            float* __restrict__ M2a, float* __restrict__ M2b,
                            int* __restrict__ H) {
  if (blockIdx.x == 0 && threadIdx.x < 128) {
    int o = threadIdx.x;
    float a0 = 0, a1 = 0, a2 = 0, b0 = 0, b1 = 0, b2 = 0;
    for (int i = 0; i < 64; ++i) {
      float w2 = W2[o * 64 + i];
      const float* w1r = W1 + i * 6;
      a0 += w2 * w1r[0]; a1 += w2 * w1r[1]; a2 += w2 * w1r[2];
      b0 += w2 * (w1r[3] - w1r[0]); b1 += w2 * (w1r[4] - w1r[1]); b2 += w2 * (w1r[5] - w1r[2]);
    }
    M2a[o * 3 + 0] = a0; M2a[o * 3 + 1] = a1; M2a[o * 3 + 2] = a2;
    M2b[o * 3 + 0] = b0; M2b[o * 3 + 1] = b1; M2b[o * 3 + 2] = b2;
  }
  int g = blockIdx.x * 128 + threadIdx.x;
  if (g < BATCH * 256) H[g] = 0;
}

// ---------- K1: p[b][j][o] = M2a[o]·x_j ; q likewise (fp16, packed pairs) ----------
__global__ __launch_bounds__(64) void pq_kernel(const float* __restrict__ x,
                                                const float* __restrict__ M2a,
                                                const float* __restrict__ M2b,
                                                unsigned short* __restrict__ p,
                                                unsigned short* __restrict__ q) {
  int b = blockIdx.x >> 6;
  int j0 = (blockIdx.x & 63) << 5;
  int t = threadIdx.x;                 // 0..63 -> channels 2t, 2t+1
  int o0 = t * 2;
  float a00 = M2a[o0 * 3 + 0], a01 = M2a[o0 * 3 + 1], a02 = M2a[o0 * 3 + 2];
  float a10 = M2a[o0 * 3 + 3], a11 = M2a[o0 * 3 + 4], a12 = M2a[o0 * 3 + 5];
  float b00 = M2b[o0 * 3 + 0], b01 = M2b[o0 * 3 + 1], b02 = M2b[o0 * 3 + 2];
  float b10 = M2b[o0 * 3 + 3], b11 = M2b[o0 * 3 + 4], b12 = M2b[o0 * 3 + 5];
  const float* xb = x + b * 3 * NPTS;
  unsigned* pw = (unsigned*)p;
  unsigned* qw = (unsigned*)q;
  for (int jj = 0; jj < 32; ++jj) {
    int j = j0 + jj;
    float x0 = xb[j], x1 = xb[NPTS + j], x2 = xb[2 * NPTS + j];
    float p0 = a00 * x0 + a01 * x1 + a02 * x2;
    float p1 = a10 * x0 + a11 * x1 + a12 * x2;
    float q0 = b00 * x0 + b01 * x1 + b02 * x2;
    float q1 = b10 * x0 + b11 * x1 + b12 * x2;
    size_t base = ((size_t)(b * NPTS + j)) * 64 + t;   // dword index
    auto hp = __builtin_amdgcn_cvt_pkrtz(p0, p1);      // v_cvt_pkrtz_f16_f32
    auto hq = __builtin_amdgcn_cvt_pkrtz(q0, q1);
    pw[base] = *(const unsigned*)&hp;
    qw[base] = *(const unsigned*)&hq;
  }
}

// ---------- K2: exact 20-NN, 4 queries per wave ----------
// R4 post-mortem: per-query LDS traffic (49KB) over the 69 TB/s LDS pipe was
// the floor (~23us at 1 query/wave). R5: 4 queries/wave share each point read
// -> LDS traffic /4. cand[] is wave-private -> pass2 + select need NO barrier.
// tau inflation (2^-18) carried from R3 (cross-pass FMA-contraction ulps).
__global__ __launch_bounds__(256) void knn_kernel(const float* __restrict__ x,
                                                  int* __restrict__ idxOut) {
  __shared__ float px[NPTS], py[NPTS], pz[NPTS];      // 24 KB, stride-4B: conflict-free
  __shared__ unsigned long long cand[4][4][128];      // 16 KB, wave-private
  int b = blockIdx.x >> 7;
  int qblk = blockIdx.x & 127;
  const float* xb = x + b * 3 * NPTS;
  for (int i = threadIdx.x; i < NPTS; i += 256) {
    px[i] = xb[i]; py[i] = xb[NPTS + i]; pz[i] = xb[2 * NPTS + i];
  }
  __syncthreads();
  int wid = threadIdx.x >> 6, lane = threadIdx.x & 63;
  int qbase = qblk * 16 + wid * 4;                    // 4 queries per wave

  float qx[4], qy[4], qz[4], mn[4];
#pragma unroll
  for (int g = 0; g < 4; ++g) {
    qx[g] = px[qbase + g]; qy[g] = py[qbase + g]; qz[g] = pz[qbase + g];
    mn[g] = 1e30f;
  }

  // pass 1: per-lane min over its 32 points, for all 4 queries (shared loads)
  for (int s = 0; s < 32; ++s) {
    int i = s * 64 + lane;
    float X = px[i], Y = py[i], Z = pz[i];
#pragma unroll
    for (int g = 0; g < 4; ++g) {
      float dx = X - qx[g], dy = Y - qy[g], dz = Z - qz[g];
      mn[g] = fminf(mn[g], dx * dx + dy * dy + dz * dz);
    }
  }

  // tau[g] = 20th-smallest lane-min (upper bound on d_(20)), inflated
  float tau[4];
#pragma unroll
  for (int g = 0; g < 4; ++g) {
    float v = mn[g];
    for (int k = 2; k <= 64; k <<= 1) {
      for (int j = k >> 1; j > 0; j >>= 1) {
        float o = __shfl_xor(v, j);
        bool low = (lane & j) == 0;
        bool up = (lane & k) == 0;
        v = (low == up) ? fminf(v, o) : fmaxf(v, o);
      }
    }
    tau[g] = __shfl(v, 19) * (1.0f + 3.8e-6f);
  }

  // pass 2: recompute (shared loads), ballot-compact candidates per query
  int cnt[4] = {0, 0, 0, 0};
  for (int s = 0; s < 32; ++s) {
    int i = s * 64 + lane;
    float X = px[i], Y = py[i], Z = pz[i];
#pragma unroll
    for (int g = 0; g < 4; ++g) {
      float dx = X - qx[g], dy = Y - qy[g], dz = Z - qz[g];
      float d = dx * dx + dy * dy + dz * dz;
      bool take = d <= tau[g];
      unsigned long long mb = __ballot(take);
      if (take) {
        int pos = cnt[g] + __popcll(mb & ((1ull << lane) - 1ull));
        if (pos < 128)
          cand[wid][g][pos] =
              (((unsigned long long)__float_as_uint(d)) << 32) | (unsigned)i;
      }
      cnt[g] += __popcll(mb);
    }
  }
  // cand written & read by the same wave: no __syncthreads needed.

  // rank-count select per query: broadcast reads (same addr all lanes = free).
  // Keys unique (index tiebreak) -> exact ranks; winners rank<20 write slot rank.
#pragma unroll
  for (int g = 0; g < 4; ++g) {
    int nc = cnt[g] < 128 ? cnt[g] : 128;
    unsigned long long k0 = (lane < nc) ? cand[wid][g][lane] : ~0ull;
    unsigned long long k1 = (lane + 64 < nc) ? cand[wid][g][lane + 64] : ~0ull;
    int r0 = 0, r1 = 0;
    for (int i = 0; i < nc; ++i) {
      unsigned long long ki = cand[wid][g][i];
      r0 += (ki < k0) ? 1 : 0;
      r1 += (ki < k1) ? 1 : 0;
    }
    long long obase = ((long long)b * NPTS + qbase + g) * KNN;
    if (lane < nc && r0 < KNN) idxOut[obase + r0] = (int)(k0 & 0xffffffffu);
    if (lane + 64 < nc && r1 < KNN) idxOut[obase + r1] = (int)(k1 & 0xffffffffu);
  }
}

// ---------- K3: h3 = relu(W3 · relu(p_j+q_n)) via MFMA, fused max-reduce ----------
// R8: restructure for matrix-pipe density. 32x32x16 MFMA, M=32 pair tile,
// 512-thread blocks (8 waves), each wave owns ONE 32-channel ntile:
//   - per wave-tile: 8 MFMAs (~258 matrix cyc) vs ~140 VALU cyc -> ~66% density
//     (was 16 MFMAs vs ~300 overhead cyc -> 46%); half the barriers per work.
//   - bfr 64->32 VGPR; grid 512 = exactly 2 blocks/CU resident, zero tail.
//   - LDS tile XOR-swizzled (unit16B ^= row&7, stride 128 shorts): 32-row
//     ds_read_b128 and the staging writes are both bank-conflict-free
//     (was 2.6M conflict cycles with the 136-short pad).
__global__ __launch_bounds__(512, 4) void gemm_max_kernel(
    const unsigned short* __restrict__ p, const unsigned short* __restrict__ q,
    const int* __restrict__ idx, const float* __restrict__ W3, int* __restrict__ H) {
  __shared__ __align__(16) unsigned short h2s[2][32 * 128];  // 16 KB double-buffered

  int b = blockIdx.x >> 5;
  int w = blockIdx.x & 31;            // 0..31
  int t = threadIdx.x;                // 0..511
  int lane = t & 63, wid = t >> 6;    // 8 waves
  int col = lane & 31, hi = lane >> 5;

  // B fragments for this wave's 32 channels: B[k][n], lane holds n=col,
  // k = kk*16 + hi*8 + j  (one-time f32->f16 convert)
  v8h bfr[8];
#pragma unroll
  for (int kk = 0; kk < 8; ++kk) {
    const float* src = W3 + (size_t)(wid * 32 + col) * 128 + kk * 16 + hi * 8;
    v8h f;
#pragma unroll
    for (int jj = 0; jj < 8; ++jj) f[jj] = (_Float16)src[jj];
    bfr[kk] = f;
  }

  const unsigned short* pB = p + (size_t)b * NPTS * 128;
  const unsigned short* qB = q + (size_t)b * NPTS * 128;
  const int* idxB = idx + (size_t)b * PAIRS;

  int pm = t >> 4;        // pair-in-tile 0..31
  int cseg = t & 15;      // 16B channel unit 0..15
  int stoff = pm * 128 + ((cseg ^ (pm & 7)) * 8);  // swizzled LDS offset (shorts)

  // prologue prefetch for first tile
  uint4 P4n, Q4n;
  {
    int pr = w * 32 + pm;
    int n0 = pr / 20;
    int j0 = idxB[pr] & (NPTS - 1);
    P4n = *(const uint4*)(pB + (size_t)j0 * 128 + cseg * 8);
    Q4n = *(const uint4*)(qB + (size_t)n0 * 128 + cseg * 8);
  }

  float vmx = 0.f;
  int buf = 0;
  for (int T = w; T < PAIRS / 32; T += 32) {   // 40 exact iterations
    // stage h2 tile (32 pairs x 128 ch, fp16) from prefetched regs
    uint4 R;
    R.x = pair_relu_h2(P4n.x, Q4n.x);
    R.y = pair_relu_h2(P4n.y, Q4n.y);
    R.z = pair_relu_h2(P4n.z, Q4n.z);
    R.w = pair_relu_h2(P4n.w, Q4n.w);
    *(uint4*)&h2s[buf][stoff] = R;
    __syncthreads();

    // prefetch next tile (consumed next iteration; latency hidden by MFMA)
    int Tn = T + 32;
    if (Tn < PAIRS / 32) {
      int prn = Tn * 32 + pm;
      int nn = prn / 20;
      int jn = idxB[prn] & (NPTS - 1);
      P4n = *(const uint4*)(pB + (size_t)jn * 128 + cseg * 8);
      Q4n = *(const uint4*)(qB + (size_t)nn * 128 + cseg * 8);
    }

    // A fragments: A[m=lane&31][k=kk*16+hi*8+j], swizzle-matched ds_read_b128
    v16f acc = {0.f};
#pragma unroll
    for (int kk = 0; kk < 8; ++kk) {
      v8h a = *(const v8h*)&h2s[buf][col * 128 + (((kk * 2 + hi) ^ (col & 7)) * 8)];
      acc = __builtin_amdgcn_mfma_f32_32x32x16_f16(a, bfr[kk], acc, 0, 0, 0);
    }
    // relu folds into max (vmx starts at 0); acc rows = pairs, col = channel
    float m0 = fmaxf(fmaxf(acc[0], acc[1]), fmaxf(acc[2], acc[3]));
    float m1 = fmaxf(fmaxf(acc[4], acc[5]), fmaxf(acc[6], acc[7]));
    float m2 = fmaxf(fmaxf(acc[8], acc[9]), fmaxf(acc[10], acc[11]));
    float m3 = fmaxf(fmaxf(acc[12], acc[13]), fmaxf(acc[14], acc[15]));
    vmx = fmaxf(vmx, fmaxf(fmaxf(m0, m1), fmaxf(m2, m3)));
    buf ^= 1;
  }

  // lanes l and l^32 hold the same channel (rows differ by 4): reduce, write
  float vv = fmaxf(vmx, __shfl_xor(vmx, 32));
  if (hi == 0) {
    int ch = wid * 32 + col;
    atomicMax(&H[b * 256 + ch], __float_as_int(vv));  // values >= 0: int order == float order
  }
}

// ---------- K4: out = H @ fc_w^T + fc_b (one wave per output element) ----------
__global__ __launch_bounds__(64) void fc_kernel(const int* __restrict__ Hi,
                                                const float* __restrict__ fcw,
                                                const float* __restrict__ fcb,
                                                float* __restrict__ out) {
  int b = blockIdx.x / 10, r = blockIdx.x % 10;
  int lane = threadIdx.x;
  const float* Hb = (const float*)Hi + b * 256;
  float s = 0.f;
#pragma unroll
  for (int c = lane; c < 256; c += 64) s += Hb[c] * fcw[r * 256 + c];
#pragma unroll
  for (int m = 32; m > 0; m >>= 1) s += __shfl_xor(s, m);
  if (lane == 0) out[b * 10 + r] = s + fcb[r];
}

// ---------- launch ----------
extern "C" void kernel_launch(void* const* d_in, const int* in_sizes, int n_in,
                              void* d_out, int out_size, void* d_ws, size_t ws_size,
                              hipStream_t stream) {
  const float* x   = (const float*)d_in[0];
  const float* W1  = (const float*)d_in[1];
  const float* W2  = (const float*)d_in[2];
  const float* W3  = (const float*)d_in[3];
  const float* fcw = (const float*)d_in[4];
  const float* fcb = (const float*)d_in[5];
  float* out = (float*)d_out;
  char* ws = (char*)d_ws;

  // workspace layout (needs ~20 MB)
  float* M2a = (float*)(ws + 0);            // 1536 B
  float* M2b = (float*)(ws + 1536);         // 1536 B
  int* H     = (int*)(ws + 4096);           // 16 KB (16x256 f32-as-int)
  int* idx   = (int*)(ws + 24576);          // 2.62 MB
  unsigned short* p = (unsigned short*)(ws + 3145728);   // 8.39 MB fp16
  unsigned short* q = (unsigned short*)(ws + 12582912);  // 8.39 MB fp16

  prep_kernel<<<32, 128, 0, stream>>>(W1, W2, M2a, M2b, H);
  pq_kernel<<<BATCH * 64, 64, 0, stream>>>(x, M2a, M2b, p, q);
  knn_kernel<<<BATCH * 128, 256, 0, stream>>>(x, idx);
  gemm_max_kernel<<<BATCH * 32, 512, 0, stream>>>(p, q, idx, W3, H);
  fc_kernel<<<BATCH * 10, 64, 0, stream>>>(H, fcw, fcb, out);
}

// Round 4
// 174.016 us; speedup vs baseline: 1.1064x; 1.0195x over previous
//
#include <hip/hip_runtime.h>
#include <stdint.h>

typedef _Float16 v8h __attribute__((ext_vector_type(8)));
typedef _Float16 v2h __attribute__((ext_vector_type(2)));
typedef float v4f __attribute__((ext_vector_type(4)));
typedef float v16f __attribute__((ext_vector_type(16)));

#define NPTS 2048
#define BATCH 16
#define KNN 20
#define PAIRS (NPTS * KNN)   // 40960 per batch

// ---------- helpers ----------
// R6/R7: fp16 pair op: 2 packed ops (v_pk_add_f16 + v_pk_max_f16).
__device__ __forceinline__ unsigned pair_relu_h2(unsigned pu, unsigned qu) {
  v2h a = *(const v2h*)&pu;
  v2h b = *(const v2h*)&qu;
  v2h s = a + b;                                   // v_pk_add_f16
  v2h z = {(_Float16)0.f, (_Float16)0.f};
  v2h r = __builtin_elementwise_max(s, z);         // v_pk_max_f16 (relu)
  return *(const unsigned*)&r;
}

// ---------- K0: fold M2a = W2*W1a, M2b = W2*(W1b-W1a); zero H ----------
__global__ void prep_kernel(const float* __restrict__ W1, const float* __restrict__ W2,
                            float* __restrict__ M2a, float* __restrict__ M2b,
                            int* __restrict__ H) {
  if (blockIdx.x == 0 && threadIdx.x < 128) {
    int o = threadIdx.x;
    float a0 = 0, a1 = 0, a2 = 0, b0 = 0, b1 = 0, b2 = 0;
    for (int i = 0; i < 64; ++i) {
      float w2 = W2[o * 64 + i];
      const float* w1r = W1 + i * 6;
      a0 += w2 * w1r[0]; a1 += w2 * w1r[1]; a2 += w2 * w1r[2];
      b0 += w2 * (w1r[3] - w1r[0]); b1 += w2 * (w1r[4] - w1r[1]); b2 += w2 * (w1r[5] - w1r[2]);
    }
    M2a[o * 3 + 0] = a0; M2a[o * 3 + 1] = a1; M2a[o * 3 + 2] = a2;
    M2b[o * 3 + 0] = b0; M2b[o * 3 + 1] = b1; M2b[o * 3 + 2] = b2;
  }
  int g = blockIdx.x * 128 + threadIdx.x;
  if (g < BATCH * 256) H[g] = 0;
}

// ---------- K1: p[b][j][o] = M2a[o]·x_j ; q likewise (fp16, packed pairs) ----------
__global__ __launch_bounds__(64) void pq_kernel(const float* __restrict__ x,
                                                const float* __restrict__ M2a,
                                                const float* __restrict__ M2b,
                                                unsigned short* __restrict__ p,
                                                unsigned short* __restrict__ q) {
  int b = blockIdx.x >> 6;
  int j0 = (blockIdx.x & 63) << 5;
  int t = threadIdx.x;                 // 0..63 -> channels 2t, 2t+1
  int o0 = t * 2;
  float a00 = M2a[o0 * 3 + 0], a01 = M2a[o0 * 3 + 1], a02 = M2a[o0 * 3 + 2];
  float a10 = M2a[o0 * 3 + 3], a11 = M2a[o0 * 3 + 4], a12 = M2a[o0 * 3 + 5];
  float b00 = M2b[o0 * 3 + 0], b01 = M2b[o0 * 3 + 1], b02 = M2b[o0 * 3 + 2];
  float b10 = M2b[o0 * 3 + 3], b11 = M2b[o0 * 3 + 4], b12 = M2b[o0 * 3 + 5];
  const float* xb = x + b * 3 * NPTS;
  unsigned* pw = (unsigned*)p;
  unsigned* qw = (unsigned*)q;
  for (int jj = 0; jj < 32; ++jj) {
    int j = j0 + jj;
    float x0 = xb[j], x1 = xb[NPTS + j], x2 = xb[2 * NPTS + j];
    float p0 = a00 * x0 + a01 * x1 + a02 * x2;
    float p1 = a10 * x0 + a11 * x1 + a12 * x2;
    float q0 = b00 * x0 + b01 * x1 + b02 * x2;
    float q1 = b10 * x0 + b11 * x1 + b12 * x2;
    size_t base = ((size_t)(b * NPTS + j)) * 64 + t;   // dword index
    auto hp = __builtin_amdgcn_cvt_pkrtz(p0, p1);      // v_cvt_pkrtz_f16_f32
    auto hq = __builtin_amdgcn_cvt_pkrtz(q0, q1);
    pw[base] = *(const unsigned*)&hp;
    qw[base] = *(const unsigned*)&hq;
  }
}

// ---------- K2: exact 20-NN, 4 queries per wave ----------
// R4 post-mortem: per-query LDS traffic (49KB) over the 69 TB/s LDS pipe was
// the floor (~23us at 1 query/wave). R5: 4 queries/wave share each point read
// -> LDS traffic /4. cand[] is wave-private -> pass2 + select need NO barrier.
// tau inflation (2^-18) carried from R3 (cross-pass FMA-contraction ulps).
__global__ __launch_bounds__(256) void knn_kernel(const float* __restrict__ x,
                                                  int* __restrict__ idxOut) {
  __shared__ float px[NPTS], py[NPTS], pz[NPTS];      // 24 KB, stride-4B: conflict-free
  __shared__ unsigned long long cand[4][4][128];      // 16 KB, wave-private
  int b = blockIdx.x >> 7;
  int qblk = blockIdx.x & 127;
  const float* xb = x + b * 3 * NPTS;
  for (int i = threadIdx.x; i < NPTS; i += 256) {
    px[i] = xb[i]; py[i] = xb[NPTS + i]; pz[i] = xb[2 * NPTS + i];
  }
  __syncthreads();
  int wid = threadIdx.x >> 6, lane = threadIdx.x & 63;
  int qbase = qblk * 16 + wid * 4;                    // 4 queries per wave

  float qx[4], qy[4], qz[4], mn[4];
#pragma unroll
  for (int g = 0; g < 4; ++g) {
    qx[g] = px[qbase + g]; qy[g] = py[qbase + g]; qz[g] = pz[qbase + g];
    mn[g] = 1e30f;
  }

  // pass 1: per-lane min over its 32 points, for all 4 queries (shared loads)
  for (int s = 0; s < 32; ++s) {
    int i = s * 64 + lane;
    float X = px[i], Y = py[i], Z = pz[i];
#pragma unroll
    for (int g = 0; g < 4; ++g) {
      float dx = X - qx[g], dy = Y - qy[g], dz = Z - qz[g];
      mn[g] = fminf(mn[g], dx * dx + dy * dy + dz * dz);
    }
  }

  // tau[g] = 20th-smallest lane-min (upper bound on d_(20)), inflated
  float tau[4];
#pragma unroll
  for (int g = 0; g < 4; ++g) {
    float v = mn[g];
    for (int k = 2; k <= 64; k <<= 1) {
      for (int j = k >> 1; j > 0; j >>= 1) {
        float o = __shfl_xor(v, j);
        bool low = (lane & j) == 0;
        bool up = (lane & k) == 0;
        v = (low == up) ? fminf(v, o) : fmaxf(v, o);
      }
    }
    tau[g] = __shfl(v, 19) * (1.0f + 3.8e-6f);
  }

  // pass 2: recompute (shared loads), ballot-compact candidates per query
  int cnt[4] = {0, 0, 0, 0};
  for (int s = 0; s < 32; ++s) {
    int i = s * 64 + lane;
    float X = px[i], Y = py[i], Z = pz[i];
#pragma unroll
    for (int g = 0; g < 4; ++g) {
      float dx = X - qx[g], dy = Y - qy[g], dz = Z - qz[g];
      float d = dx * dx + dy * dy + dz * dz;
      bool take = d <= tau[g];
      unsigned long long mb = __ballot(take);
      if (take) {
        int pos = cnt[g] + __popcll(mb & ((1ull << lane) - 1ull));
        if (pos < 128)
          cand[wid][g][pos] =
              (((unsigned long long)__float_as_uint(d)) << 32) | (unsigned)i;
      }
      cnt[g] += __popcll(mb);
    }
  }
  // cand written & read by the same wave: no __syncthreads needed.

  // rank-count select per query: broadcast reads (same addr all lanes = free).
  // Keys unique (index tiebreak) -> exact ranks; winners rank<20 write slot rank.
#pragma unroll
  for (int g = 0; g < 4; ++g) {
    int nc = cnt[g] < 128 ? cnt[g] : 128;
    unsigned long long k0 = (lane < nc) ? cand[wid][g][lane] : ~0ull;
    unsigned long long k1 = (lane + 64 < nc) ? cand[wid][g][lane + 64] : ~0ull;
    int r0 = 0, r1 = 0;
    for (int i = 0; i < nc; ++i) {
      unsigned long long ki = cand[wid][g][i];
      r0 += (ki < k0) ? 1 : 0;
      r1 += (ki < k1) ? 1 : 0;
    }
    long long obase = ((long long)b * NPTS + qbase + g) * KNN;
    if (lane < nc && r0 < KNN) idxOut[obase + r0] = (int)(k0 & 0xffffffffu);
    if (lane + 64 < nc && r1 < KNN) idxOut[obase + r1] = (int)(k1 & 0xffffffffu);
  }
}

// ---------- K3: h3 = relu(W3 · relu(p_j+q_n)) via MFMA, fused max-reduce ----------
// R9: fix two R8 regressions + LDS amplification:
//  (a) b = blockIdx & 15 restored: batch b's blocks all map to XCD b%8
//      (R8's b=blockIdx>>5 scattered 16 batches across every XCD -> 16MB
//      working set vs 4MB L2 -> FETCH 10->57MB, gathers at L3/HBM latency).
//  (b) 4-wave blocks, each wave computes TWO 32-ch ntiles per shared a[kk]
//      read: LDS wave-ops per tile 72 -> 40 (LDS pipe was ~67% busy, the
//      binding resource; MFMA only 31%).
//  (c) idx prefetched 2 tiles ahead, p/q 1 ahead: the idx->gather 2x200cy
//      serial chain no longer must fit in one compute window.
__global__ __launch_bounds__(256, 3) void gemm_max_kernel(
    const unsigned short* __restrict__ p, const unsigned short* __restrict__ q,
    const int* __restrict__ idx, const float* __restrict__ W3, int* __restrict__ H) {
  __shared__ __align__(16) unsigned short h2s[2][32 * 128];  // 16 KB double-buffered

  int b = blockIdx.x & 15;
  int w = blockIdx.x >> 4;            // 0..47
  int t = threadIdx.x;                // 0..255
  int lane = t & 63, wid = t >> 6;    // 4 waves
  int col = lane & 31, hi = lane >> 5;

  // B fragments: wave owns channels [wid*64, wid*64+64) as 2 ntiles.
  // B[k][n]: lane holds n = ntl-base + col, k = kk*16 + hi*8 + j.
  v8h bfr0[8], bfr1[8];
#pragma unroll
  for (int kk = 0; kk < 8; ++kk) {
    const float* s0 = W3 + (size_t)(wid * 64 + col) * 128 + kk * 16 + hi * 8;
    const float* s1 = s0 + 32 * 128;
    v8h f0, f1;
#pragma unroll
    for (int jj = 0; jj < 8; ++jj) { f0[jj] = (_Float16)s0[jj]; f1[jj] = (_Float16)s1[jj]; }
    bfr0[kk] = f0; bfr1[kk] = f1;
  }

  const unsigned short* pB = p + (size_t)b * NPTS * 128;
  const unsigned short* qB = q + (size_t)b * NPTS * 128;
  const int* idxB = idx + (size_t)b * PAIRS;

  int pm = t >> 3;        // pair-in-tile 0..31
  int c2 = t & 7;         // covers 16B units 2*c2, 2*c2+1 (32B of the row)
  // swizzled LDS store offsets (shorts): unit u -> u ^ (row&7)
  int st0 = pm * 128 + (((c2 * 2) ^ (pm & 7)) * 8);
  int st1 = pm * 128 + (((c2 * 2 + 1) ^ (pm & 7)) * 8);

  const int NT = PAIRS / 32;          // 1280 tiles/batch; stride 48 (26-27 iters)

  // prologue: loads for tile w; idx one tile ahead
  uint4 P0, P1, Q0, Q1;
  int jn = 0;
  {
    int pr = w * 32 + pm;
    int j = idxB[pr] & (NPTS - 1);
    int n = pr / 20;
    P0 = *(const uint4*)(pB + (size_t)j * 128 + c2 * 16);
    P1 = *(const uint4*)(pB + (size_t)j * 128 + c2 * 16 + 8);
    Q0 = *(const uint4*)(qB + (size_t)n * 128 + c2 * 16);
    Q1 = *(const uint4*)(qB + (size_t)n * 128 + c2 * 16 + 8);
    int T1 = w + 48;
    if (T1 < NT) jn = idxB[T1 * 32 + pm];
  }

  float vmx0 = 0.f, vmx1 = 0.f;
  int buf = 0;
  for (int T = w; T < NT; T += 48) {
    // stage h2 tile (32 pairs x 128 ch, fp16) from prefetched regs
    uint4 R0, R1;
    R0.x = pair_relu_h2(P0.x, Q0.x); R0.y = pair_relu_h2(P0.y, Q0.y);
    R0.z = pair_relu_h2(P0.z, Q0.z); R0.w = pair_relu_h2(P0.w, Q0.w);
    R1.x = pair_relu_h2(P1.x, Q1.x); R1.y = pair_relu_h2(P1.y, Q1.y);
    R1.z = pair_relu_h2(P1.z, Q1.z); R1.w = pair_relu_h2(P1.w, Q1.w);
    *(uint4*)&h2s[buf][st0] = R0;
    *(uint4*)&h2s[buf][st1] = R1;
    __syncthreads();   // one barrier/iter: dbuf covers the read-vs-overwrite hazard

    // prefetch tile T+48 (p-row from jn loaded last iter); idx for T+96
    int Tn = T + 48;
    if (Tn < NT) {
      int prn = Tn * 32 + pm;
      int j = jn & (NPTS - 1);
      int n = prn / 20;
      P0 = *(const uint4*)(pB + (size_t)j * 128 + c2 * 16);
      P1 = *(const uint4*)(pB + (size_t)j * 128 + c2 * 16 + 8);
      Q0 = *(const uint4*)(qB + (size_t)n * 128 + c2 * 16);
      Q1 = *(const uint4*)(qB + (size_t)n * 128 + c2 * 16 + 8);
      int T2 = T + 96;
      if (T2 < NT) jn = idxB[T2 * 32 + pm];
    }

    // compute: one a[kk] read feeds both ntiles (16 MFMA per 8 ds_read)
    v16f acc0 = {0.f}, acc1 = {0.f};
#pragma unroll
    for (int kk = 0; kk < 8; ++kk) {
      v8h a = *(const v8h*)&h2s[buf][col * 128 + (((kk * 2 + hi) ^ (col & 7)) * 8)];
      acc0 = __builtin_amdgcn_mfma_f32_32x32x16_f16(a, bfr0[kk], acc0, 0, 0, 0);
      acc1 = __builtin_amdgcn_mfma_f32_32x32x16_f16(a, bfr1[kk], acc1, 0, 0, 0);
    }
    // relu folds into max (vmx starts at 0); acc rows = pairs, col = channel
    float a0 = fmaxf(fmaxf(acc0[0], acc0[1]), fmaxf(acc0[2], acc0[3]));
    float a1 = fmaxf(fmaxf(acc0[4], acc0[5]), fmaxf(acc0[6], acc0[7]));
    float a2 = fmaxf(fmaxf(acc0[8], acc0[9]), fmaxf(acc0[10], acc0[11]));
    float a3 = fmaxf(fmaxf(acc0[12], acc0[13]), fmaxf(acc0[14], acc0[15]));
    vmx0 = fmaxf(vmx0, fmaxf(fmaxf(a0, a1), fmaxf(a2, a3)));
    float c0 = fmaxf(fmaxf(acc1[0], acc1[1]), fmaxf(acc1[2], acc1[3]));
    float c1 = fmaxf(fmaxf(acc1[4], acc1[5]), fmaxf(acc1[6], acc1[7]));
    float c2v = fmaxf(fmaxf(acc1[8], acc1[9]), fmaxf(acc1[10], acc1[11]));
    float c3 = fmaxf(fmaxf(acc1[12], acc1[13]), fmaxf(acc1[14], acc1[15]));
    vmx1 = fmaxf(vmx1, fmaxf(fmaxf(c0, c1), fmaxf(c2v, c3)));
    buf ^= 1;
  }

  // lanes l and l^32 hold the same channel (complementary rows): reduce, write
  float v0 = fmaxf(vmx0, __shfl_xor(vmx0, 32));
  float v1 = fmaxf(vmx1, __shfl_xor(vmx1, 32));
  if (hi == 0) {
    atomicMax(&H[b * 256 + wid * 64 + col], __float_as_int(v0));
    atomicMax(&H[b * 256 + wid * 64 + 32 + col], __float_as_int(v1));
  }
}

// ---------- K4: out = H @ fc_w^T + fc_b (one wave per output element) ----------
__global__ __launch_bounds__(64) void fc_kernel(const int* __restrict__ Hi,
                                                const float* __restrict__ fcw,
                                                const float* __restrict__ fcb,
                                                float* __restrict__ out) {
  int b = blockIdx.x / 10, r = blockIdx.x % 10;
  int lane = threadIdx.x;
  const float* Hb = (const float*)Hi + b * 256;
  float s = 0.f;
#pragma unroll
  for (int c = lane; c < 256; c += 64) s += Hb[c] * fcw[r * 256 + c];
#pragma unroll
  for (int m = 32; m > 0; m >>= 1) s += __shfl_xor(s, m);
  if (lane == 0) out[b * 10 + r] = s + fcb[r];
}

// ---------- launch ----------
extern "C" void kernel_launch(void* const* d_in, const int* in_sizes, int n_in,
                              void* d_out, int out_size, void* d_ws, size_t ws_size,
                              hipStream_t stream) {
  const float* x   = (const float*)d_in[0];
  const float* W1  = (const float*)d_in[1];
  const float* W2  = (const float*)d_in[2];
  const float* W3  = (const float*)d_in[3];
  const float* fcw = (const float*)d_in[4];
  const float* fcb = (const float*)d_in[5];
  float* out = (float*)d_out;
  char* ws = (char*)d_ws;

  // workspace layout (needs ~20 MB)
  float* M2a = (float*)(ws + 0);            // 1536 B
  float* M2b = (float*)(ws + 1536);         // 1536 B
  int* H     = (int*)(ws + 4096);           // 16 KB (16x256 f32-as-int)
  int* idx   = (int*)(ws + 24576);          // 2.62 MB
  unsigned short* p = (unsigned short*)(ws + 3145728);   // 8.39 MB fp16
  unsigned short* q = (unsigned short*)(ws + 12582912);  // 8.39 MB fp16

  prep_kernel<<<32, 128, 0, stream>>>(W1, W2, M2a, M2b, H);
  pq_kernel<<<BATCH * 64, 64, 0, stream>>>(x, M2a, M2b, p, q);
  knn_kernel<<<BATCH * 128, 256, 0, stream>>>(x, idx);
  gemm_max_kernel<<<BATCH * 48, 256, 0, stream>>>(p, q, idx, W3, H);
  fc_kernel<<<BATCH * 10, 64, 0, stream>>>(H, fcw, fcb, out);
}

// Round 5
// 164.448 us; speedup vs baseline: 1.1707x; 1.0582x over previous
//
#include <hip/hip_runtime.h>
#include <stdint.h>

typedef _Float16 v8h __attribute__((ext_vector_type(8)));
typedef _Float16 v2h __attribute__((ext_vector_type(2)));
typedef float v4f __attribute__((ext_vector_type(4)));
typedef float v16f __attribute__((ext_vector_type(16)));

#define NPTS 2048
#define BATCH 16
#define KNN 20
#define PAIRS (NPTS * KNN)   // 40960 per batch

// ---------- helpers ----------
// R6/R7: fp16 pair op: 2 packed ops (v_pk_add_f16 + v_pk_max_f16).
__device__ __forceinline__ unsigned pair_relu_h2(unsigned pu, unsigned qu) {
  v2h a = *(const v2h*)&pu;
  v2h b = *(const v2h*)&qu;
  v2h s = a + b;                                   // v_pk_add_f16
  v2h z = {(_Float16)0.f, (_Float16)0.f};
  v2h r = __builtin_elementwise_max(s, z);         // v_pk_max_f16 (relu)
  return *(const unsigned*)&r;
}

// ---------- K0: fold M2a = W2*W1a, M2b = W2*(W1b-W1a); zero H ----------
__global__ void prep_kernel(const float* __restrict__ W1, const float* __restrict__ W2,
                            float* __restrict__ M2a, float* __restrict__ M2b,
                            int* __restrict__ H) {
  if (blockIdx.x == 0 && threadIdx.x < 128) {
    int o = threadIdx.x;
    float a0 = 0, a1 = 0, a2 = 0, b0 = 0, b1 = 0, b2 = 0;
    for (int i = 0; i < 64; ++i) {
      float w2 = W2[o * 64 + i];
      const float* w1r = W1 + i * 6;
      a0 += w2 * w1r[0]; a1 += w2 * w1r[1]; a2 += w2 * w1r[2];
      b0 += w2 * (w1r[3] - w1r[0]); b1 += w2 * (w1r[4] - w1r[1]); b2 += w2 * (w1r[5] - w1r[2]);
    }
    M2a[o * 3 + 0] = a0; M2a[o * 3 + 1] = a1; M2a[o * 3 + 2] = a2;
    M2b[o * 3 + 0] = b0; M2b[o * 3 + 1] = b1; M2b[o * 3 + 2] = b2;
  }
  int g = blockIdx.x * 128 + threadIdx.x;
  if (g < BATCH * 256) H[g] = 0;
}

// ---------- K1: p[b][j][o] = M2a[o]·x_j ; q likewise (fp16, packed pairs) ----------
__global__ __launch_bounds__(64) void pq_kernel(const float* __restrict__ x,
                                                const float* __restrict__ M2a,
                                                const float* __restrict__ M2b,
                                                unsigned short* __restrict__ p,
                                                unsigned short* __restrict__ q) {
  int b = blockIdx.x >> 6;
  int j0 = (blockIdx.x & 63) << 5;
  int t = threadIdx.x;                 // 0..63 -> channels 2t, 2t+1
  int o0 = t * 2;
  float a00 = M2a[o0 * 3 + 0], a01 = M2a[o0 * 3 + 1], a02 = M2a[o0 * 3 + 2];
  float a10 = M2a[o0 * 3 + 3], a11 = M2a[o0 * 3 + 4], a12 = M2a[o0 * 3 + 5];
  float b00 = M2b[o0 * 3 + 0], b01 = M2b[o0 * 3 + 1], b02 = M2b[o0 * 3 + 2];
  float b10 = M2b[o0 * 3 + 3], b11 = M2b[o0 * 3 + 4], b12 = M2b[o0 * 3 + 5];
  const float* xb = x + b * 3 * NPTS;
  unsigned* pw = (unsigned*)p;
  unsigned* qw = (unsigned*)q;
  for (int jj = 0; jj < 32; ++jj) {
    int j = j0 + jj;
    float x0 = xb[j], x1 = xb[NPTS + j], x2 = xb[2 * NPTS + j];
    float p0 = a00 * x0 + a01 * x1 + a02 * x2;
    float p1 = a10 * x0 + a11 * x1 + a12 * x2;
    float q0 = b00 * x0 + b01 * x1 + b02 * x2;
    float q1 = b10 * x0 + b11 * x1 + b12 * x2;
    size_t base = ((size_t)(b * NPTS + j)) * 64 + t;   // dword index
    auto hp = __builtin_amdgcn_cvt_pkrtz(p0, p1);      // v_cvt_pkrtz_f16_f32
    auto hq = __builtin_amdgcn_cvt_pkrtz(q0, q1);
    pw[base] = *(const unsigned*)&hp;
    qw[base] = *(const unsigned*)&hq;
  }
}

// ---------- K2: exact 20-NN ----------
// R10: knn was the top dispatch (53us, VALUBusy 76%, MfmaUtil 0) -> pure
// VALU-inst-count bound. Cuts:
//  (a) norm trick: stage (x,y,z,|x|^2) float4; d' = nrm - 2 q.x via 3 FMA
//      (was 3 sub + 3 fma); 1 ds_read_b128 w/ static offset (was 3 b32).
//      d' = |x-q|^2 - |q|^2 (order-preserving; can be negative -> sort key
//      is float_as_uint(d'+64), monotone since d' > -64 for this data).
//  (b) 8 queries/wave + 512-thr blocks: halves shared overhead & staging;
//      grid 512 = exactly 2 blocks/CU, LDS 64KB -> occupancy 35->50%.
//  (c) 64 cand slots (E[cnt]~23, P(>64) ~6 sigma): single-key rank-count.
//  tau inflation sign-safe for negative d': t + |t|*4e-6 + 1e-6.
__global__ __launch_bounds__(512, 4) void knn_kernel(const float* __restrict__ x,
                                                     int* __restrict__ idxOut) {
  __shared__ float4 pts[NPTS];                    // 32 KB (x,y,z,|.|^2)
  __shared__ unsigned long long cand[8][8][64];   // 32 KB, wave-private
  int b = blockIdx.x >> 5;
  int qblk = blockIdx.x & 31;
  const float* xb = x + b * 3 * NPTS;
  for (int i = threadIdx.x; i < NPTS; i += 512) {
    float X = xb[i], Y = xb[NPTS + i], Z = xb[2 * NPTS + i];
    pts[i] = make_float4(X, Y, Z, X * X + Y * Y + Z * Z);
  }
  __syncthreads();
  int wid = threadIdx.x >> 6, lane = threadIdx.x & 63;
  int qbase = qblk * 64 + wid * 8;                // 8 queries per wave

  float m2x[8], m2y[8], m2z[8], mn[8];
#pragma unroll
  for (int g = 0; g < 8; ++g) {
    float4 qp = pts[qbase + g];                   // broadcast read
    m2x[g] = -2.f * qp.x; m2y[g] = -2.f * qp.y; m2z[g] = -2.f * qp.z;
    mn[g] = 1e30f;
  }

  // pass 1: per-lane min over its 32 points, all 8 queries share the load
  for (int s = 0; s < 32; ++s) {
    float4 P = pts[s * 64 + lane];
#pragma unroll
    for (int g = 0; g < 8; ++g) {
      float d = fmaf(m2x[g], P.x, fmaf(m2y[g], P.y, fmaf(m2z[g], P.z, P.w)));
      mn[g] = fminf(mn[g], d);
    }
  }

  // tau[g] = 20th-smallest lane-min (upper bound on d'_(20)), inflated
  float tau[8];
#pragma unroll
  for (int g = 0; g < 8; ++g) {
    float v = mn[g];
    for (int k = 2; k <= 64; k <<= 1) {
      for (int j = k >> 1; j > 0; j >>= 1) {
        float o = __shfl_xor(v, j);
        bool low = (lane & j) == 0;
        bool up = (lane & k) == 0;
        v = (low == up) ? fminf(v, o) : fmaxf(v, o);
      }
    }
    float t = __shfl(v, 19);
    tau[g] = t + fabsf(t) * 4e-6f + 1e-6f;
  }

  // pass 2: recompute, ballot-compact candidates per query
  int cnt[8] = {0, 0, 0, 0, 0, 0, 0, 0};
  for (int s = 0; s < 32; ++s) {
    int i = s * 64 + lane;
    float4 P = pts[i];
#pragma unroll
    for (int g = 0; g < 8; ++g) {
      float d = fmaf(m2x[g], P.x, fmaf(m2y[g], P.y, fmaf(m2z[g], P.z, P.w)));
      bool take = d <= tau[g];
      unsigned long long mb = __ballot(take);
      if (take) {
        int pos = cnt[g] + __popcll(mb & ((1ull << lane) - 1ull));
        if (pos < 64) {
          unsigned kd = __float_as_uint(d + 64.f);   // d > -64: monotone key
          cand[wid][g][pos] = (((unsigned long long)kd) << 32) | (unsigned)i;
        }
      }
      cnt[g] += __popcll(mb);
    }
  }
  // cand written & read by the same wave: no __syncthreads needed.

  // rank-count select: broadcast reads (same addr all lanes = free).
  // Keys unique (index tiebreak) -> exact ranks; >=20 candidates guaranteed
  // (>=20 lanes have lane-min <= tau, each contributes >=1).
#pragma unroll
  for (int g = 0; g < 8; ++g) {
    int nc = cnt[g] < 64 ? cnt[g] : 64;
    unsigned long long k0 = (lane < nc) ? cand[wid][g][lane] : ~0ull;
    int r0 = 0;
    for (int i = 0; i < nc; ++i) r0 += (cand[wid][g][i] < k0) ? 1 : 0;
    long long obase = ((long long)b * NPTS + qbase + g) * KNN;
    if (lane < nc && r0 < KNN) idxOut[obase + r0] = (int)(k0 & 0xffffffffu);
  }
}

// ---------- K3: h3 = relu(W3 · relu(p_j+q_n)) via MFMA, fused max-reduce ----------
// R9: fix two R8 regressions + LDS amplification:
//  (a) b = blockIdx & 15 restored: batch b's blocks all map to XCD b%8
//      (R8's b=blockIdx>>5 scattered 16 batches across every XCD -> 16MB
//      working set vs 4MB L2 -> FETCH 10->57MB, gathers at L3/HBM latency).
//  (b) 4-wave blocks, each wave computes TWO 32-ch ntiles per shared a[kk]
//      read: LDS wave-ops per tile 72 -> 40 (LDS pipe was ~67% busy, the
//      binding resource; MFMA only 31%).
//  (c) idx prefetched 2 tiles ahead, p/q 1 ahead: the idx->gather 2x200cy
//      serial chain no longer must fit in one compute window.
__global__ __launch_bounds__(256, 3) void gemm_max_kernel(
    const unsigned short* __restrict__ p, const unsigned short* __restrict__ q,
    const int* __restrict__ idx, const float* __restrict__ W3, int* __restrict__ H) {
  __shared__ __align__(16) unsigned short h2s[2][32 * 128];  // 16 KB double-buffered

  int b = blockIdx.x & 15;
  int w = blockIdx.x >> 4;            // 0..47
  int t = threadIdx.x;                // 0..255
  int lane = t & 63, wid = t >> 6;    // 4 waves
  int col = lane & 31, hi = lane >> 5;

  // B fragments: wave owns channels [wid*64, wid*64+64) as 2 ntiles.
  // B[k][n]: lane holds n = ntl-base + col, k = kk*16 + hi*8 + j.
  v8h bfr0[8], bfr1[8];
#pragma unroll
  for (int kk = 0; kk < 8; ++kk) {
    const float* s0 = W3 + (size_t)(wid * 64 + col) * 128 + kk * 16 + hi * 8;
    const float* s1 = s0 + 32 * 128;
    v8h f0, f1;
#pragma unroll
    for (int jj = 0; jj < 8; ++jj) { f0[jj] = (_Float16)s0[jj]; f1[jj] = (_Float16)s1[jj]; }
    bfr0[kk] = f0; bfr1[kk] = f1;
  }

  const unsigned short* pB = p + (size_t)b * NPTS * 128;
  const unsigned short* qB = q + (size_t)b * NPTS * 128;
  const int* idxB = idx + (size_t)b * PAIRS;

  int pm = t >> 3;        // pair-in-tile 0..31
  int c2 = t & 7;         // covers 16B units 2*c2, 2*c2+1 (32B of the row)
  // swizzled LDS store offsets (shorts): unit u -> u ^ (row&7)
  int st0 = pm * 128 + (((c2 * 2) ^ (pm & 7)) * 8);
  int st1 = pm * 128 + (((c2 * 2 + 1) ^ (pm & 7)) * 8);

  const int NT = PAIRS / 32;          // 1280 tiles/batch; stride 48 (26-27 iters)

  // prologue: loads for tile w; idx one tile ahead
  uint4 P0, P1, Q0, Q1;
  int jn = 0;
  {
    int pr = w * 32 + pm;
    int j = idxB[pr] & (NPTS - 1);
    int n = pr / 20;
    P0 = *(const uint4*)(pB + (size_t)j * 128 + c2 * 16);
    P1 = *(const uint4*)(pB + (size_t)j * 128 + c2 * 16 + 8);
    Q0 = *(const uint4*)(qB + (size_t)n * 128 + c2 * 16);
    Q1 = *(const uint4*)(qB + (size_t)n * 128 + c2 * 16 + 8);
    int T1 = w + 48;
    if (T1 < NT) jn = idxB[T1 * 32 + pm];
  }

  float vmx0 = 0.f, vmx1 = 0.f;
  int buf = 0;
  for (int T = w; T < NT; T += 48) {
    // stage h2 tile (32 pairs x 128 ch, fp16) from prefetched regs
    uint4 R0, R1;
    R0.x = pair_relu_h2(P0.x, Q0.x); R0.y = pair_relu_h2(P0.y, Q0.y);
    R0.z = pair_relu_h2(P0.z, Q0.z); R0.w = pair_relu_h2(P0.w, Q0.w);
    R1.x = pair_relu_h2(P1.x, Q1.x); R1.y = pair_relu_h2(P1.y, Q1.y);
    R1.z = pair_relu_h2(P1.z, Q1.z); R1.w = pair_relu_h2(P1.w, Q1.w);
    *(uint4*)&h2s[buf][st0] = R0;
    *(uint4*)&h2s[buf][st1] = R1;
    __syncthreads();   // one barrier/iter: dbuf covers the read-vs-overwrite hazard

    // prefetch tile T+48 (p-row from jn loaded last iter); idx for T+96
    int Tn = T + 48;
    if (Tn < NT) {
      int prn = Tn * 32 + pm;
      int j = jn & (NPTS - 1);
      int n = prn / 20;
      P0 = *(const uint4*)(pB + (size_t)j * 128 + c2 * 16);
      P1 = *(const uint4*)(pB + (size_t)j * 128 + c2 * 16 + 8);
      Q0 = *(const uint4*)(qB + (size_t)n * 128 + c2 * 16);
      Q1 = *(const uint4*)(qB + (size_t)n * 128 + c2 * 16 + 8);
      int T2 = T + 96;
      if (T2 < NT) jn = idxB[T2 * 32 + pm];
    }

    // compute: one a[kk] read feeds both ntiles (16 MFMA per 8 ds_read)
    v16f acc0 = {0.f}, acc1 = {0.f};
#pragma unroll
    for (int kk = 0; kk < 8; ++kk) {
      v8h a = *(const v8h*)&h2s[buf][col * 128 + (((kk * 2 + hi) ^ (col & 7)) * 8)];
      acc0 = __builtin_amdgcn_mfma_f32_32x32x16_f16(a, bfr0[kk], acc0, 0, 0, 0);
      acc1 = __builtin_amdgcn_mfma_f32_32x32x16_f16(a, bfr1[kk], acc1, 0, 0, 0);
    }
    // relu folds into max (vmx starts at 0); acc rows = pairs, col = channel
    float a0 = fmaxf(fmaxf(acc0[0], acc0[1]), fmaxf(acc0[2], acc0[3]));
    float a1 = fmaxf(fmaxf(acc0[4], acc0[5]), fmaxf(acc0[6], acc0[7]));
    float a2 = fmaxf(fmaxf(acc0[8], acc0[9]), fmaxf(acc0[10], acc0[11]));
    float a3 = fmaxf(fmaxf(acc0[12], acc0[13]), fmaxf(acc0[14], acc0[15]));
    vmx0 = fmaxf(vmx0, fmaxf(fmaxf(a0, a1), fmaxf(a2, a3)));
    float c0 = fmaxf(fmaxf(acc1[0], acc1[1]), fmaxf(acc1[2], acc1[3]));
    float c1 = fmaxf(fmaxf(acc1[4], acc1[5]), fmaxf(acc1[6], acc1[7]));
    float c2v = fmaxf(fmaxf(acc1[8], acc1[9]), fmaxf(acc1[10], acc1[11]));
    float c3 = fmaxf(fmaxf(acc1[12], acc1[13]), fmaxf(acc1[14], acc1[15]));
    vmx1 = fmaxf(vmx1, fmaxf(fmaxf(c0, c1), fmaxf(c2v, c3)));
    buf ^= 1;
  }

  // lanes l and l^32 hold the same channel (complementary rows): reduce, write
  float v0 = fmaxf(vmx0, __shfl_xor(vmx0, 32));
  float v1 = fmaxf(vmx1, __shfl_xor(vmx1, 32));
  if (hi == 0) {
    atomicMax(&H[b * 256 + wid * 64 + col], __float_as_int(v0));
    atomicMax(&H[b * 256 + wid * 64 + 32 + col], __float_as_int(v1));
  }
}

// ---------- K4: out = H @ fc_w^T + fc_b (one wave per output element) ----------
__global__ __launch_bounds__(64) void fc_kernel(const int* __restrict__ Hi,
                                                const float* __restrict__ fcw,
                                                const float* __restrict__ fcb,
                                                float* __restrict__ out) {
  int b = blockIdx.x / 10, r = blockIdx.x % 10;
  int lane = threadIdx.x;
  const float* Hb = (const float*)Hi + b * 256;
  float s = 0.f;
#pragma unroll
  for (int c = lane; c < 256; c += 64) s += Hb[c] * fcw[r * 256 + c];
#pragma unroll
  for (int m = 32; m > 0; m >>= 1) s += __shfl_xor(s, m);
  if (lane == 0) out[b * 10 + r] = s + fcb[r];
}

// ---------- launch ----------
extern "C" void kernel_launch(void* const* d_in, const int* in_sizes, int n_in,
                              void* d_out, int out_size, void* d_ws, size_t ws_size,
                              hipStream_t stream) {
  const float* x   = (const float*)d_in[0];
  const float* W1  = (const float*)d_in[1];
  const float* W2  = (const float*)d_in[2];
  const float* W3  = (const float*)d_in[3];
  const float* fcw = (const float*)d_in[4];
  const float* fcb = (const float*)d_in[5];
  float* out = (float*)d_out;
  char* ws = (char*)d_ws;

  // workspace layout (needs ~20 MB)
  float* M2a = (float*)(ws + 0);            // 1536 B
  float* M2b = (float*)(ws + 1536);         // 1536 B
  int* H     = (int*)(ws + 4096);           // 16 KB (16x256 f32-as-int)
  int* idx   = (int*)(ws + 24576);          // 2.62 MB
  unsigned short* p = (unsigned short*)(ws + 3145728);   // 8.39 MB fp16
  unsigned short* q = (unsigned short*)(ws + 12582912);  // 8.39 MB fp16

  prep_kernel<<<32, 128, 0, stream>>>(W1, W2, M2a, M2b, H);
  pq_kernel<<<BATCH * 64, 64, 0, stream>>>(x, M2a, M2b, p, q);
  knn_kernel<<<BATCH * 32, 512, 0, stream>>>(x, idx);
  gemm_max_kernel<<<BATCH * 48, 256, 0, stream>>>(p, q, idx, W3, H);
  fc_kernel<<<BATCH * 10, 64, 0, stream>>>(H, fcw, fcb, out);
}